// Round 14
// baseline (37.180 us; speedup 1.0000x reference)
//
#include <hip/hip_runtime.h>
#include <hip/hip_bf16.h>

// out[i][j] = (x@beta)[i][j] - 0.1*y[i][j]*||beta[:,j]||_1
//             + (4096*rowsum(W2)[j] + bias2[j] + bias_lin[j])
// M=4096, K=2048, N=1024. adv==1 always.
//
// Round 14: 32x32x16 fp8 MFMA (2x FLOP per ds_read_b128 vs 16x16, ~20% better
// MFMA rate). K-permuted fp8 storage: within each 128-k span, 16B unit
// u = 2j+h holds k = j*32 + h*8 + {0..7} ++ {16..23}  (j=slice-pair 0..3,
// h=lane>>5 half). One b128 read = the operand pair for k-slices (2j, 2j+1).
// Gemm: 512 thr / 8 waves = 2k x 2m x 2n (wave tile 64x32, K-split), BM=128
// BN=64 BKu=128 (NT=16), 3 LDS bufs (72KB, 2 blocks/CU), lookahead-2 gll16
// (r12-identical staging addresses), counted vmcnt(3), ^(row&7) unit swizzle,
// K-half merge via freed staging LDS, fused epilogue (32x32 C/D mapping).

typedef float    f32x4  __attribute__((ext_vector_type(4)));
typedef float    f32x16 __attribute__((ext_vector_type(16)));
typedef unsigned u32x4  __attribute__((ext_vector_type(4)));
typedef long     lx2    __attribute__((ext_vector_type(2)));

constexpr int M = 4096;
constexpr int N = 1024;
constexpr int K = 2048;
constexpr int NHID = 4096;

__device__ __forceinline__ unsigned pk4f8(float a, float b, float c, float d) {
    unsigned v = __builtin_amdgcn_cvt_pk_fp8_f32(a, b, 0, false);
    v = __builtin_amdgcn_cvt_pk_fp8_f32(c, d, v, true);
    return v;
}

__device__ __forceinline__ void gll16(const void* g, void* l) {
    __builtin_amdgcn_global_load_lds(
        (const __attribute__((address_space(1))) void*)g,
        (__attribute__((address_space(3))) void*)l, 16, 0, 0);
}

// =================== pre ====================================================
// grid 1792: [0,1024) x 64x128 tiles -> xb fp8 (32x32-permuted);
//            [1024,1536) beta 64x64 tiles -> bt fp8 permuted + L1 partials;
//            [1536,1792) W2 row sums.
__global__ void __launch_bounds__(256) pre_kernel(
    const float* __restrict__ x, const float* __restrict__ beta,
    const float* __restrict__ W2,
    char* __restrict__ xb, char* __restrict__ bt,
    float* __restrict__ partials,   // [32][1024]
    float* __restrict__ wsum) {     // [1024]
    __shared__ float tls[64 * 132];
    const int bx = blockIdx.x, tid = threadIdx.x;
    if (bx < 1024) {
        const int rt = bx >> 4, kt = bx & 15;
        {   // phase 1: 64x128 f32 tile -> LDS
            const int r = tid >> 2, c0 = (tid & 3) * 32;
            const float* src = x + (size_t)(rt * 64 + r) * K + kt * 128 + c0;
            #pragma unroll
            for (int i = 0; i < 8; ++i)
                *(f32x4*)&tls[r * 132 + c0 + i * 4] = *(const f32x4*)(src + i * 4);
        }
        __syncthreads();
        {   // phase 2: permuted fp8 pack; unit u=2j+h: k = j*32+h*8+{0..7,16..23}
            const int r = tid >> 2;
            const float* row = &tls[r * 132];
            char* orow = xb + (size_t)(rt * 64 + r) * K + kt * 128;
            #pragma unroll
            for (int uu = 0; uu < 2; ++uu) {
                const int u = (tid & 3) + uu * 4;
                const int j = u >> 1, h = u & 1;
                const float* h0 = row + j * 32 + h * 8;        // slice 2j
                const float* h1 = h0 + 16;                     // slice 2j+1
                u32x4 o = { pk4f8(h0[0], h0[1], h0[2], h0[3]),
                            pk4f8(h0[4], h0[5], h0[6], h0[7]),
                            pk4f8(h1[0], h1[1], h1[2], h1[3]),
                            pk4f8(h1[4], h1[5], h1[6], h1[7]) };
                *(u32x4*)(orow + u * 16) = o;
            }
        }
    } else if (bx < 1536) {
        const int tile = bx - 1024, tk = tile & 31, tn = tile >> 5;
        {   // phase 1: beta[k][n] 64x64 -> LDS
            const int r = tid >> 2, c0 = (tid & 3) * 16;
            const float* src = beta + (size_t)(tk * 64 + r) * N + tn * 64 + c0;
            #pragma unroll
            for (int j = 0; j < 4; ++j)
                *(f32x4*)&tls[r * 68 + c0 + j * 4] = *(const f32x4*)(src + j * 4);
        }
        __syncthreads();
        {   // phase 2: transpose + permuted fp8 + column-L1 (4-lane shfl)
            // thread q handles unit u = 4*(tk&1)+q; k_tile = (q>>1)*32+(q&1)*8
            const int n = tid >> 2, q = tid & 3;
            const int kb = (q >> 1) * 32 + (q & 1) * 8;
            float s = 0.f;
            float v0[8], v1[8];
            #pragma unroll
            for (int jj = 0; jj < 8; ++jj) {
                v0[jj] = tls[(kb + jj) * 68 + n];
                v1[jj] = tls[(kb + 16 + jj) * 68 + n];
                s += fabsf(v0[jj]) + fabsf(v1[jj]);
            }
            s += __shfl_xor(s, 1);
            s += __shfl_xor(s, 2);
            if (q == 0) partials[tk * 1024 + tn * 64 + n] = s;
            u32x4 o = { pk4f8(v0[0], v0[1], v0[2], v0[3]),
                        pk4f8(v0[4], v0[5], v0[6], v0[7]),
                        pk4f8(v1[0], v1[1], v1[2], v1[3]),
                        pk4f8(v1[4], v1[5], v1[6], v1[7]) };
            *(u32x4*)(bt + (size_t)(tn * 64 + n) * K + tk * 64 + q * 16) = o;
        }
    } else {
        const int b = bx - 1536;
        const int wv = tid >> 6, lane = tid & 63;
        const int row = b * 4 + wv;
        const f32x4* w4 = (const f32x4*)(W2 + (size_t)row * NHID);
        float acc = 0.f;
        #pragma unroll
        for (int i = 0; i < 16; ++i) {
            f32x4 v = w4[i * 64 + lane];
            acc += v[0] + v[1] + v[2] + v[3];
        }
        #pragma unroll
        for (int off = 32; off; off >>= 1) acc += __shfl_down(acc, off);
        if (lane == 0) wsum[row] = acc;
    }
}

// =================== main GEMM: 32x32x16 fp8, K-split, 3-buf vmcnt(3) =======
constexpr int BKu = 128;
constexpr int NT  = K / BKu;         // 16
constexpr int ASZ = 128 * BKu;       // 16384 B
constexpr int BSZ = 64 * BKu;        // 8192 B

__global__ void __launch_bounds__(512, 4) gemm_kernel(
    const char* __restrict__ xb, const char* __restrict__ bt,
    const float* __restrict__ y,
    const float* __restrict__ partials, const float* __restrict__ wsum,
    const float* __restrict__ bias_lin, const float* __restrict__ bias2,
    float* __restrict__ out) {
    __shared__ __align__(16) char Al[3 * ASZ];   // 48KB (merge scratch later)
    __shared__ __align__(16) char Bl[3 * BSZ];   // 24KB

    const int tid = threadIdx.x, lane = tid & 63, w = tid >> 6;   // w: 0..7
    const int wk = w >> 2, wm = (w >> 1) & 1, wn = w & 1;         // 2k x 2m x 2n
    const int c = blockIdx.x & 7, local = blockIdx.x >> 3;
    const int mb = ((c & 1) << 4) + (local >> 2);
    const int nb = ((c >> 1) << 2) + (local & 3);
    const int brow = mb * 128, bcol = nb * 64;

    // ---- staging (identical addresses to round 12; proven fast) ----
    const int srow = lane >> 3;
    const int sulog = (lane & 7) ^ srow;
    const char* asrc0 = xb + (size_t)(brow + w * 16 + srow) * K + sulog * 16;
    const char* asrc1 = asrc0 + (size_t)8 * K;
    const char* bsrc  = bt + (size_t)(bcol + w * 8 + srow) * K + sulog * 16;

    auto STAGE = [&](int buf, int t) {
        gll16(asrc0 + t * BKu, &Al[buf * ASZ + w * 2048]);
        gll16(asrc1 + t * BKu, &Al[buf * ASZ + w * 2048 + 1024]);
        gll16(bsrc  + t * BKu, &Bl[buf * BSZ + w * 1024]);
    };

    // ---- fragment read offsets: unit u = 2j + h, phys slot = u^(row&7) ----
    const int rl = lane & 31, h = lane >> 5;
    int aoff[2][2], boff[2];
    #pragma unroll
    for (int m = 0; m < 2; ++m)
        #pragma unroll
        for (int jj = 0; jj < 2; ++jj) {
            const int j = wk * 2 + jj;
            const int row = wm * 64 + m * 32 + rl;
            aoff[m][jj] = row * 128 + (((2 * j + h) ^ (row & 7)) * 16);
        }
    #pragma unroll
    for (int jj = 0; jj < 2; ++jj) {
        const int j = wk * 2 + jj;
        const int row = wn * 32 + rl;
        boff[jj] = row * 128 + (((2 * j + h) ^ (row & 7)) * 16);
    }

    f32x16 acc0 = (f32x16)0.f, acc1 = (f32x16)0.f;

    auto COMPUTE = [&](int buf) {
        const char* A = &Al[buf * ASZ];
        const char* B = &Bl[buf * BSZ];
        #pragma unroll
        for (int jj = 0; jj < 2; ++jj) {
            lx2 a0 = *(const lx2*)&A[aoff[0][jj]];
            lx2 a1 = *(const lx2*)&A[aoff[1][jj]];
            lx2 b  = *(const lx2*)&B[boff[jj]];
            acc0 = __builtin_amdgcn_mfma_f32_32x32x16_fp8_fp8(a0.x, b.x, acc0, 0, 0, 0);
            acc1 = __builtin_amdgcn_mfma_f32_32x32x16_fp8_fp8(a1.x, b.x, acc1, 0, 0, 0);
            acc0 = __builtin_amdgcn_mfma_f32_32x32x16_fp8_fp8(a0.y, b.y, acc0, 0, 0, 0);
            acc1 = __builtin_amdgcn_mfma_f32_32x32x16_fp8_fp8(a1.y, b.y, acc1, 0, 0, 0);
        }
    };

    STAGE(0, 0);
    STAGE(1, 1);
    for (int t = 0; t < NT; ++t) {
        if (t < NT - 1) { asm volatile("s_waitcnt vmcnt(3)" ::: "memory"); }
        else            { asm volatile("s_waitcnt vmcnt(0)" ::: "memory"); }
        __builtin_amdgcn_s_barrier();
        __builtin_amdgcn_sched_barrier(0);
        if (t + 2 < NT) STAGE((t + 2) % 3, t + 2);
        COMPUTE(t % 3);
    }

    // ---- K-half merge: wk=1 waves dump acc into Al (free), wk=0 adds ----
    __syncthreads();
    float* mrg = (float*)Al;   // 4 slots x 8KB = 32KB <= 48KB
    if (wk == 1) {
        const int base = (w - 4) * 2048 + lane * 16;
        #pragma unroll
        for (int i = 0; i < 4; ++i) {
            f32x4 v0 = { acc0[i * 4], acc0[i * 4 + 1], acc0[i * 4 + 2], acc0[i * 4 + 3] };
            f32x4 v1 = { acc1[i * 4], acc1[i * 4 + 1], acc1[i * 4 + 2], acc1[i * 4 + 3] };
            *(f32x4*)&mrg[base + i * 4]        = v0;
            *(f32x4*)&mrg[base + 1024 + i * 4] = v1;
        }
    }
    __syncthreads();
    if (wk == 0) {
        const int base = w * 2048 + lane * 16;
        #pragma unroll
        for (int i = 0; i < 4; ++i) {
            f32x4 v0 = *(const f32x4*)&mrg[base + i * 4];
            f32x4 v1 = *(const f32x4*)&mrg[base + 1024 + i * 4];
            #pragma unroll
            for (int e = 0; e < 4; ++e) {
                acc0[i * 4 + e] += v0[e];
                acc1[i * 4 + e] += v1[e];
            }
        }
        // ---- epilogue: 32x32 C/D: col=lane&31, row=(reg&3)+8*(reg>>2)+4*h ----
        const int gc = bcol + wn * 32 + rl;
        float bsum = 0.f;
        #pragma unroll 8
        for (int tk = 0; tk < 32; ++tk) bsum += partials[tk * 1024 + gc];
        const float be = 0.1f * bsum;
        const float ct = bias_lin[gc] + bias2[gc] + (float)NHID * wsum[gc];
        #pragma unroll
        for (int m = 0; m < 2; ++m) {
            const int rbase = brow + wm * 64 + m * 32 + 4 * h;
            #pragma unroll
            for (int g = 0; g < 4; ++g) {
                #pragma unroll
                for (int jr = 0; jr < 4; ++jr) {
                    const int row = rbase + g * 8 + jr;
                    const size_t idx = (size_t)row * N + gc;
                    const float a = (m == 0) ? acc0[g * 4 + jr] : acc1[g * 4 + jr];
                    out[idx] = a + ct - be * y[idx];
                }
            }
        }
    }
}

extern "C" void kernel_launch(void* const* d_in, const int* in_sizes, int n_in,
                              void* d_out, int out_size, void* d_ws, size_t ws_size,
                              hipStream_t stream) {
    const float* x        = (const float*)d_in[0];
    const float* y        = (const float*)d_in[1];
    const float* beta     = (const float*)d_in[2];
    const float* bias_lin = (const float*)d_in[3];
    const float* W2       = (const float*)d_in[5];
    const float* bias2    = (const float*)d_in[7];
    float* out = (float*)d_out;

    float* partials = (float*)d_ws;                        // [32][1024]
    float* wsum     = partials + 32 * 1024;                // [1024]
    char*  xb       = (char*)(wsum + 1024);                // [M][K] fp8 permuted
    char*  bts      = xb + (size_t)M * K;                  // [N][K] fp8 permuted

    pre_kernel<<<1792, 256, 0, stream>>>(x, beta, W2, xb, bts, partials, wsum);
    gemm_kernel<<<512, 512, 0, stream>>>(xb, bts, y, partials, wsum,
                                         bias_lin, bias2, out);
}